// Round 7
// baseline (271.717 us; speedup 1.0000x reference)
//
#include <hip/hip_runtime.h>
#include <hip/hip_bf16.h>
#include <math.h>

// fp32 I/O confirmed. index_sample is int32.
// R4: k_measure float4-lane layout (187 -> ~50us, issue-bound fix).
// R6: k_topk was 52.7us at 0.3% occupancy (1 wave/bh, 40 dependent
// argmax iterations, latency-bound). Replaced with LDS bitonic sort of
// packed u64 keys (orderable-float<<32 | ~idx): 66 passes, 256 thr/bh,
// tie -> lowest index preserved. Expect ~5us.

#define BB 4
#define LL 2048
#define HH 8
#define DD 64
#define SS 40
#define UU 40
#define CC 64
#define LC (LL/CC)    // 32 (cumsum chunking)

#define KC   64       // staged k-tile rows
#define NBIG 8        // split-K output granularity
#define NSUB 4        // sub-tiles per block (NBIG*NSUB*KC == LL)
#define KPAD 68       // K/V LDS row stride (floats), 272B: 16B-aligned, bank-spread
#define PPAD 68

// ---------------------------------------------------------------------------
// K1: sparsity measure M[bh*L + i] = max_s(Q_i . K_idx[i,s]) - sum_s(...)/L
// one wave per query. lane = (sg = lane>>4, d4 = lane&15); 4 samples/iter.
// ---------------------------------------------------------------------------
__global__ void k_measure(const float* __restrict__ Q, const float* __restrict__ K,
                          const int* __restrict__ idx, float* __restrict__ M)
{
    int tid  = threadIdx.x;
    int lane = tid & 63;
    int wave = tid >> 6;
    int qid  = blockIdx.x * 4 + wave;          // qid = bh*L + i
    int bh = qid / LL;  int i = qid - bh * LL;
    int b  = bh / HH;   int h = bh - b * HH;

    int sg = lane >> 4;                        // sample group 0..3
    int d4 = lane & 15;                        // float4 slice of d

    const float* qrow = Q + (((size_t)b * LL + i) * HH + h) * DD;
    float4 qv = *(const float4*)(qrow + d4 * 4);

    const float* Kh = K + ((size_t)b * LL * HH + h) * DD;   // + kk*HH*DD
    const int* ip = idx + (size_t)i * SS;

    float maxv = -INFINITY, sumv = 0.f;
    #pragma unroll
    for (int s0 = 0; s0 < SS; s0 += 4) {
        int kk = ip[s0 + sg];                  // 4 distinct addrs, 16-lane broadcast
        const float* krow = Kh + (size_t)kk * (HH * DD);
        float4 kv = *(const float4*)(krow + d4 * 4);
        float p = qv.x * kv.x;
        p = fmaf(qv.y, kv.y, p);
        p = fmaf(qv.z, kv.z, p);
        p = fmaf(qv.w, kv.w, p);
        // reduce over the 16 d4-lanes (stays within sample group)
        p += __shfl_xor(p, 1);
        p += __shfl_xor(p, 2);
        p += __shfl_xor(p, 4);
        p += __shfl_xor(p, 8);
        maxv = fmaxf(maxv, p);
        sumv += p;
    }
    // combine the 4 sample groups
    maxv = fmaxf(maxv, __shfl_xor(maxv, 16));
    sumv += __shfl_xor(sumv, 16);
    maxv = fmaxf(maxv, __shfl_xor(maxv, 32));
    sumv += __shfl_xor(sumv, 32);

    if (lane == 0) M[qid] = maxv - sumv * (1.0f / (float)LL);
}

// ---------------------------------------------------------------------------
// K2: top-40 per (b,h) via LDS bitonic sort. One block (256 thr) per bh.
// Key = orderable(u32 of float) << 32 | ~idx  — descending sort gives
// top-k by value with ties broken toward the lowest index.
// Only the SET of top-40 matters downstream (scatter is per-position).
// ---------------------------------------------------------------------------
__global__ void k_topk(const float* __restrict__ M, int* __restrict__ topIdx)
{
    __shared__ unsigned long long s[LL];      // 16 KB
    int tid = threadIdx.x;
    int bh  = blockIdx.x;
    const float* Mp = M + (size_t)bh * LL;

    for (int i = tid; i < LL; i += 256) {
        unsigned u = __float_as_uint(Mp[i]);
        u = (u & 0x80000000u) ? ~u : (u | 0x80000000u);   // order-preserving map
        s[i] = ((unsigned long long)u << 32) | (unsigned)(~i);
    }
    __syncthreads();

    for (int k = 2; k <= LL; k <<= 1) {
        for (int j = k >> 1; j > 0; j >>= 1) {
            for (int t = tid; t < LL; t += 256) {
                int l = t ^ j;
                if (l > t) {
                    unsigned long long a = s[t], c = s[l];
                    bool desc = (t & k) == 0;
                    if (desc ? (a < c) : (a > c)) { s[t] = c; s[l] = a; }
                }
            }
            __syncthreads();
        }
    }

    if (tid < UU) {
        unsigned low = (unsigned)s[tid];
        topIdx[bh * UU + tid] = (int)(~low);
    }
}

// ---------------------------------------------------------------------------
// K3: flash attention, 8-way split-K with online softmax inside the block.
// Grid = bh(32) x big-chunk(8), 256 threads. Each block sweeps NSUB=4
// 64-row sub-tiles: stage K/V -> LDS; QK with lane-owned K-row and
// scalar-loaded Q rows (pos wave-uniform); per-u online m/l update;
// register O accumulators rescaled per sub-tile. Emits m,l,O per big-chunk.
// ---------------------------------------------------------------------------
__launch_bounds__(256, 1)
__global__ void k_attn_flash(const float* __restrict__ Q, const float* __restrict__ K,
                             const float* __restrict__ V, const int* __restrict__ topIdx,
                             float* __restrict__ mc, float* __restrict__ lc,
                             float* __restrict__ Oc)
{
    __shared__ float sK[KC][KPAD];
    __shared__ float sV[KC][KPAD];
    __shared__ float sP[UU][PPAD];
    __shared__ int   sPos[UU];
    __shared__ float sM[UU], sL[UU], sScale[UU];

    int t   = threadIdx.x;
    int bh  = blockIdx.x / NBIG, big = blockIdx.x % NBIG;
    int b   = bh / HH, h = bh % HH;

    if (t < UU) {
        sPos[t]   = topIdx[bh * UU + t];
        sM[t]     = -INFINITY;
        sL[t]     = 0.f;
    }

    // persistent O accumulators: thread = (d4p = t&15, ug = t>>4)
    int d4p = t & 15, ug = t >> 4;
    int u0 = ug, u1 = 16 + ug, u2 = 32 + ug;
    int u2c = (u2 < UU) ? u2 : (UU - 1);       // clamped; result discarded
    float4 a0 = {0,0,0,0}, a1 = {0,0,0,0}, a2 = {0,0,0,0};

    int j  = t & 63;                            // QK lane -> K row
    int w  = t >> 6, lane = t & 63;             // softmax wave mapping
    int ub = __builtin_amdgcn_readfirstlane(w) * 10;

    for (int sub = 0; sub < NSUB; ++sub) {
        int k0 = (big * NSUB + sub) * KC;
        __syncthreads();   // previous Phase D (and sub=0 sPos write) done

        // ---- stage K/V tile (64 rows x 64 floats), coalesced float4 ----
        const float* Kbase = K + (((size_t)b * LL + k0) * HH + h) * DD;
        const float* Vbase = V + (((size_t)b * LL + k0) * HH + h) * DD;
        #pragma unroll
        for (int it = 0; it < 4; ++it) {
            int flat = it * 256 + t;            // 0..1023
            int r = flat >> 4, d4 = flat & 15;
            float4 kk = *(const float4*)(Kbase + (size_t)r * (HH * DD) + d4 * 4);
            float4 vv = *(const float4*)(Vbase + (size_t)r * (HH * DD) + d4 * 4);
            *(float4*)&sK[r][d4 * 4] = kk;
            *(float4*)&sV[r][d4 * 4] = vv;
        }
        __syncthreads();

        // ---- QK: lane owns K row j; Q rows via scalar (wave-uniform) loads ----
        int jg = k0 + j;
        float kreg[DD];
        #pragma unroll
        for (int d4 = 0; d4 < 16; ++d4) {
            float4 kk = *(const float4*)&sK[j][d4 * 4];
            kreg[d4 * 4 + 0] = kk.x; kreg[d4 * 4 + 1] = kk.y;
            kreg[d4 * 4 + 2] = kk.z; kreg[d4 * 4 + 3] = kk.w;
        }
        #pragma unroll
        for (int iu = 0; iu < 10; iu += 5) {
            int p0 = __builtin_amdgcn_readfirstlane(sPos[ub + iu + 0]);
            int p1 = __builtin_amdgcn_readfirstlane(sPos[ub + iu + 1]);
            int p2 = __builtin_amdgcn_readfirstlane(sPos[ub + iu + 2]);
            int p3 = __builtin_amdgcn_readfirstlane(sPos[ub + iu + 3]);
            int p4 = __builtin_amdgcn_readfirstlane(sPos[ub + iu + 4]);
            const float* q0 = Q + (((size_t)b * LL + p0) * HH + h) * DD;
            const float* q1 = Q + (((size_t)b * LL + p1) * HH + h) * DD;
            const float* q2 = Q + (((size_t)b * LL + p2) * HH + h) * DD;
            const float* q3 = Q + (((size_t)b * LL + p3) * HH + h) * DD;
            const float* q4 = Q + (((size_t)b * LL + p4) * HH + h) * DD;
            float c0 = 0.f, c1 = 0.f, c2 = 0.f, c3 = 0.f, c4 = 0.f;
            #pragma unroll
            for (int d = 0; d < DD; ++d) {
                float kd = kreg[d];
                c0 = fmaf(q0[d], kd, c0);
                c1 = fmaf(q1[d], kd, c1);
                c2 = fmaf(q2[d], kd, c2);
                c3 = fmaf(q3[d], kd, c3);
                c4 = fmaf(q4[d], kd, c4);
            }
            sP[ub + iu + 0][j] = (jg > p0) ? -INFINITY : c0 * 0.125f;
            sP[ub + iu + 1][j] = (jg > p1) ? -INFINITY : c1 * 0.125f;
            sP[ub + iu + 2][j] = (jg > p2) ? -INFINITY : c2 * 0.125f;
            sP[ub + iu + 3][j] = (jg > p3) ? -INFINITY : c3 * 0.125f;
            sP[ub + iu + 4][j] = (jg > p4) ? -INFINITY : c4 * 0.125f;
        }
        __syncthreads();

        // ---- online softmax stats; wave w handles u = w*10 .. +9 ----
        for (int i = 0; i < 10; ++i) {
            int u = w * 10 + i;
            float s0 = sP[u][lane];
            float mchunk = s0;
            #pragma unroll
            for (int off = 1; off < 64; off <<= 1)
                mchunk = fmaxf(mchunk, __shfl_xor(mchunk, off));
            float mold = sM[u];
            float mnew = fmaxf(mold, mchunk);
            float e = (mnew == -INFINITY) ? 0.f : __expf(s0 - mnew);
            float lch = e;
            #pragma unroll
            for (int off = 1; off < 64; off <<= 1) lch += __shfl_xor(lch, off);
            float scale = (mold == -INFINITY) ? 0.f : __expf(mold - mnew);
            sP[u][lane] = e;
            if (lane == 0) {
                sM[u] = mnew;
                sL[u] = sL[u] * scale + lch;
                sScale[u] = scale;
            }
        }
        __syncthreads();

        // ---- PV accumulate with rescale ----
        float sc0 = sScale[u0], sc1 = sScale[u1], sc2 = sScale[u2c];
        a0.x *= sc0; a0.y *= sc0; a0.z *= sc0; a0.w *= sc0;
        a1.x *= sc1; a1.y *= sc1; a1.z *= sc1; a1.w *= sc1;
        a2.x *= sc2; a2.y *= sc2; a2.z *= sc2; a2.w *= sc2;
        #pragma unroll 4
        for (int j4 = 0; j4 < KC / 4; ++j4) {
            float4 pj0 = *(const float4*)&sP[u0][j4 * 4];
            float4 pj1 = *(const float4*)&sP[u1][j4 * 4];
            float4 pj2 = *(const float4*)&sP[u2c][j4 * 4];
            float4 va = *(const float4*)&sV[j4 * 4 + 0][d4p * 4];
            float4 vb = *(const float4*)&sV[j4 * 4 + 1][d4p * 4];
            float4 vc = *(const float4*)&sV[j4 * 4 + 2][d4p * 4];
            float4 vd = *(const float4*)&sV[j4 * 4 + 3][d4p * 4];
            a0.x = fmaf(pj0.x, va.x, fmaf(pj0.y, vb.x, fmaf(pj0.z, vc.x, fmaf(pj0.w, vd.x, a0.x))));
            a0.y = fmaf(pj0.x, va.y, fmaf(pj0.y, vb.y, fmaf(pj0.z, vc.y, fmaf(pj0.w, vd.y, a0.y))));
            a0.z = fmaf(pj0.x, va.z, fmaf(pj0.y, vb.z, fmaf(pj0.z, vc.z, fmaf(pj0.w, vd.z, a0.z))));
            a0.w = fmaf(pj0.x, va.w, fmaf(pj0.y, vb.w, fmaf(pj0.z, vc.w, fmaf(pj0.w, vd.w, a0.w))));
            a1.x = fmaf(pj1.x, va.x, fmaf(pj1.y, vb.x, fmaf(pj1.z, vc.x, fmaf(pj1.w, vd.x, a1.x))));
            a1.y = fmaf(pj1.x, va.y, fmaf(pj1.y, vb.y, fmaf(pj1.z, vc.y, fmaf(pj1.w, vd.y, a1.y))));
            a1.z = fmaf(pj1.x, va.z, fmaf(pj1.y, vb.z, fmaf(pj1.z, vc.z, fmaf(pj1.w, vd.z, a1.z))));
            a1.w = fmaf(pj1.x, va.w, fmaf(pj1.y, vb.w, fmaf(pj1.z, vc.w, fmaf(pj1.w, vd.w, a1.w))));
            a2.x = fmaf(pj2.x, va.x, fmaf(pj2.y, vb.x, fmaf(pj2.z, vc.x, fmaf(pj2.w, vd.x, a2.x))));
            a2.y = fmaf(pj2.x, va.y, fmaf(pj2.y, vb.y, fmaf(pj2.z, vc.y, fmaf(pj2.w, vd.y, a2.y))));
            a2.z = fmaf(pj2.x, va.z, fmaf(pj2.y, vb.z, fmaf(pj2.z, vc.z, fmaf(pj2.w, vd.z, a2.z))));
            a2.w = fmaf(pj2.x, va.w, fmaf(pj2.y, vb.w, fmaf(pj2.z, vc.w, fmaf(pj2.w, vd.w, a2.w))));
        }
    }
    __syncthreads();

    int cidx = (bh * NBIG + big) * UU;
    float* ob = Oc + (size_t)cidx * DD;
    *(float4*)&ob[u0 * DD + d4p * 4] = a0;
    *(float4*)&ob[u1 * DD + d4p * 4] = a1;
    if (u2 < UU) *(float4*)&ob[u2 * DD + d4p * 4] = a2;
    if (t < UU) { mc[cidx + t] = sM[t]; lc[cidx + t] = sL[t]; }
}

// ---------------------------------------------------------------------------
// K4: combine the 8 big-chunk partials and write into out rows.
// Must run after k_cumsum. Grid = 32 bh, 256 threads.
// ---------------------------------------------------------------------------
__global__ void k_combine(const float* __restrict__ mc, const float* __restrict__ lc,
                          const float* __restrict__ Oc, const int* __restrict__ topIdx,
                          float* __restrict__ out)
{
    int bh = blockIdx.x;
    int b  = bh / HH, h = bh % HH;
    int t  = threadIdx.x;
    int d  = t & 63, ug = t >> 6;
    for (int i = 0; i < 10; ++i) {
        int u = ug * 10 + i;
        int pos = topIdx[bh * UU + u];
        float Mx = -INFINITY;
        for (int c = 0; c < NBIG; ++c)
            Mx = fmaxf(Mx, mc[(bh * NBIG + c) * UU + u]);
        float Os = 0.f, Ls = 0.f;
        for (int c = 0; c < NBIG; ++c) {
            int ci = (bh * NBIG + c) * UU + u;
            float m = mc[ci];
            float wgt = (m == -INFINITY) ? 0.f : __expf(m - Mx);
            Ls += wgt * lc[ci];
            Os += wgt * Oc[(size_t)ci * DD + d];
        }
        out[(((size_t)b * LL + pos) * HH + h) * DD + d] = Os / Ls;
    }
}

// ---------------------------------------------------------------------------
// K5a: per-chunk sums of V along L (for cumsum). Block = 64 threads.
// ---------------------------------------------------------------------------
__global__ void k_chunksum(const float* __restrict__ V, float* __restrict__ chunkSum)
{
    int lane = threadIdx.x;
    int c  = blockIdx.x % CC;
    int bh = blockIdx.x / CC;
    int b  = bh / HH; int h = bh - b * HH;
    float acc = 0.f;
    int l0 = c * LC;
    for (int l = l0; l < l0 + LC; ++l)
        acc += V[(((size_t)b * LL + l) * HH + h) * DD + lane];
    chunkSum[((size_t)bh * CC + c) * DD + lane] = acc;
}

// ---------------------------------------------------------------------------
// K5b: cumsum with chunk-offset, write fp32 output (B,L,H,D layout).
// ---------------------------------------------------------------------------
__global__ void k_cumsum(const float* __restrict__ V, const float* __restrict__ chunkSum,
                         float* __restrict__ out)
{
    int lane = threadIdx.x;
    int c  = blockIdx.x % CC;
    int bh = blockIdx.x / CC;
    int b  = bh / HH; int h = bh - b * HH;

    float off = 0.f;
    for (int c2 = 0; c2 < c; ++c2)
        off += chunkSum[((size_t)bh * CC + c2) * DD + lane];

    float acc = off;
    int l0 = c * LC;
    for (int l = l0; l < l0 + LC; ++l) {
        size_t p = (((size_t)b * LL + l) * HH + h) * DD + lane;
        acc += V[p];
        out[p] = acc;
    }
}

// ---------------------------------------------------------------------------
extern "C" void kernel_launch(void* const* d_in, const int* in_sizes, int n_in,
                              void* d_out, int out_size, void* d_ws, size_t ws_size,
                              hipStream_t stream)
{
    const float* Q   = (const float*)d_in[0];
    const float* K   = (const float*)d_in[1];
    const float* V   = (const float*)d_in[2];
    const int*   idx = (const int*)d_in[3];
    float* out = (float*)d_out;

    // ws layout (floats) — total ~874K floats ≈ 3.5 MB
    float* M        = (float*)d_ws;                               // 65536
    int*   topIdx   = (int*)(M + (size_t)BB * HH * LL);           // 1280
    float* mc       = (float*)(topIdx + BB * HH * UU);            // 32*NBIG*UU
    float* lc       = mc + (size_t)BB * HH * NBIG * UU;           // 32*NBIG*UU
    float* Oc       = lc + (size_t)BB * HH * NBIG * UU;           // 32*NBIG*UU*DD
    float* chunkSum = Oc + (size_t)BB * HH * NBIG * UU * DD;      // 32*CC*DD

    k_measure   <<<BB * HH * LL / 4, 256, 0, stream>>>(Q, K, idx, M);
    k_topk      <<<BB * HH,          256, 0, stream>>>(M, topIdx);
    k_attn_flash<<<BB * HH * NBIG,   256, 0, stream>>>(Q, K, V, topIdx, mc, lc, Oc);
    k_chunksum  <<<BB * HH * CC,      64, 0, stream>>>(V, chunkSum);
    k_cumsum    <<<BB * HH * CC,      64, 0, stream>>>(V, chunkSum, out);
    k_combine   <<<BB * HH,          256, 0, stream>>>(mc, lc, Oc, topIdx, out);
}

// Round 8
// 209.933 us; speedup vs baseline: 1.2943x; 1.2943x over previous
//
#include <hip/hip_runtime.h>
#include <hip/hip_bf16.h>
#include <math.h>

// fp32 I/O confirmed. index_sample is int32.
// R4: k_measure float4-lane layout (187 -> ~50us, issue-bound fix).
// R7 POST-MORTEM: bitonic-sort topk REGRESSED (52.7 -> 81.7us): 66 passes of
// dependent LDS round-trips + barriers with 32 blocks = no latency hiding.
// R8: topk = register-resident binary search for the rank-40 threshold
// (32 shuffle-reduce rounds, zero LDS/barriers) + idx-tiebreak sub-search.
// Only the SET of top-40 matters downstream (scatter is per-position).

#define BB 4
#define LL 2048
#define HH 8
#define DD 64
#define SS 40
#define UU 40
#define CC 64
#define LC (LL/CC)    // 32 (cumsum chunking)

#define KC   64       // staged k-tile rows
#define NBIG 8        // split-K output granularity
#define NSUB 4        // sub-tiles per block (NBIG*NSUB*KC == LL)
#define KPAD 68       // K/V LDS row stride (floats), 272B: 16B-aligned, bank-spread
#define PPAD 68

// ---------------------------------------------------------------------------
// K1: sparsity measure M[bh*L + i] = max_s(Q_i . K_idx[i,s]) - sum_s(...)/L
// one wave per query. lane = (sg = lane>>4, d4 = lane&15); 4 samples/iter.
// ---------------------------------------------------------------------------
__global__ void k_measure(const float* __restrict__ Q, const float* __restrict__ K,
                          const int* __restrict__ idx, float* __restrict__ M)
{
    int tid  = threadIdx.x;
    int lane = tid & 63;
    int wave = tid >> 6;
    int qid  = blockIdx.x * 4 + wave;          // qid = bh*L + i
    int bh = qid / LL;  int i = qid - bh * LL;
    int b  = bh / HH;   int h = bh - b * HH;

    int sg = lane >> 4;                        // sample group 0..3
    int d4 = lane & 15;                        // float4 slice of d

    const float* qrow = Q + (((size_t)b * LL + i) * HH + h) * DD;
    float4 qv = *(const float4*)(qrow + d4 * 4);

    const float* Kh = K + ((size_t)b * LL * HH + h) * DD;   // + kk*HH*DD
    const int* ip = idx + (size_t)i * SS;

    float maxv = -INFINITY, sumv = 0.f;
    #pragma unroll
    for (int s0 = 0; s0 < SS; s0 += 4) {
        int kk = ip[s0 + sg];                  // 4 distinct addrs, 16-lane broadcast
        const float* krow = Kh + (size_t)kk * (HH * DD);
        float4 kv = *(const float4*)(krow + d4 * 4);
        float p = qv.x * kv.x;
        p = fmaf(qv.y, kv.y, p);
        p = fmaf(qv.z, kv.z, p);
        p = fmaf(qv.w, kv.w, p);
        // reduce over the 16 d4-lanes (stays within sample group)
        p += __shfl_xor(p, 1);
        p += __shfl_xor(p, 2);
        p += __shfl_xor(p, 4);
        p += __shfl_xor(p, 8);
        maxv = fmaxf(maxv, p);
        sumv += p;
    }
    // combine the 4 sample groups
    maxv = fmaxf(maxv, __shfl_xor(maxv, 16));
    sumv += __shfl_xor(sumv, 16);
    maxv = fmaxf(maxv, __shfl_xor(maxv, 32));
    sumv += __shfl_xor(sumv, 32);

    if (lane == 0) M[qid] = maxv - sumv * (1.0f / (float)LL);
}

// ---------------------------------------------------------------------------
// K2: top-40 per (b,h). One WAVE per bh, 2048 orderable keys in registers.
// Binary search the key space for T = 40th-largest; include key > T plus
// the (40 - #>T) lowest-index keys == T (exact jax.lax.top_k set).
// Zero LDS, zero barriers — shortest possible dependent chain at occupancy
// 32 waves/GPU (latency-bound regime, see R7 post-mortem).
// ---------------------------------------------------------------------------
__global__ void k_topk(const float* __restrict__ M, int* __restrict__ topIdx)
{
    int lane = threadIdx.x;      // 64
    int bh   = blockIdx.x;
    const float* Mp = M + (size_t)bh * LL;

    unsigned k[32];
    #pragma unroll
    for (int r = 0; r < 32; ++r) {
        unsigned u = __float_as_uint(Mp[r * 64 + lane]);
        k[r] = (u & 0x80000000u) ? ~u : (u | 0x80000000u);  // order-preserving
    }

    // T = max t with count(key >= t) >= UU  (== the UU-th largest key)
    unsigned T = 0u;
    for (int bit = 31; bit >= 0; --bit) {
        unsigned cand = T | (1u << bit);
        int c = 0;
        #pragma unroll
        for (int r = 0; r < 32; ++r) c += (k[r] >= cand) ? 1 : 0;
        #pragma unroll
        for (int off = 1; off < 64; off <<= 1) c += __shfl_xor(c, off);
        if (c >= UU) T = cand;
    }

    int cGT = 0, cGE = 0;
    #pragma unroll
    for (int r = 0; r < 32; ++r) {
        cGT += (k[r] > T) ? 1 : 0;
        cGE += (k[r] >= T) ? 1 : 0;
    }
    #pragma unroll
    for (int off = 1; off < 64; off <<= 1) {
        cGT += __shfl_xor(cGT, off);
        cGE += __shfl_xor(cGE, off);
    }

    int need = UU - cGT;            // how many ==T elements to include
    int X = LL;                     // include all ==T by default (m == need)
    if (cGE - cGT != need) {
        // m > need: keep the `need` lowest indices among ==T.
        // lo2 = max x with count(==T && idx < x) < need  ->  X = lo2+1
        int lo2 = 0;
        for (int bit = 10; bit >= 0; --bit) {
            int cand = lo2 | (1 << bit);
            int c = 0;
            #pragma unroll
            for (int r = 0; r < 32; ++r)
                c += (k[r] == T && (r * 64 + lane) < cand) ? 1 : 0;
            #pragma unroll
            for (int off = 1; off < 64; off <<= 1) c += __shfl_xor(c, off);
            if (c < need) lo2 = cand;
        }
        X = lo2 + 1;
    }

    // emit: pack the in-set indices into topIdx[bh*UU .. +UU) (order arbitrary)
    unsigned inMask = 0u;
    int cnt = 0;
    #pragma unroll
    for (int r = 0; r < 32; ++r) {
        bool in = (k[r] > T) || (k[r] == T && (r * 64 + lane) < X);
        if (in) { inMask |= 1u << r; ++cnt; }
    }
    int pre = cnt;
    #pragma unroll
    for (int off = 1; off < 64; off <<= 1) {
        int v = __shfl_up(pre, off);
        if (lane >= off) pre += v;
    }
    int slot = pre - cnt;
    #pragma unroll
    for (int r = 0; r < 32; ++r) {
        if ((inMask >> r) & 1u) {
            topIdx[bh * UU + slot] = r * 64 + lane;
            ++slot;
        }
    }
}

// ---------------------------------------------------------------------------
// K3: flash attention, 8-way split-K with online softmax inside the block.
// Grid = bh(32) x big-chunk(8), 256 threads. Each block sweeps NSUB=4
// 64-row sub-tiles: stage K/V -> LDS; QK with lane-owned K-row and
// scalar-loaded Q rows (pos wave-uniform); per-u online m/l update;
// register O accumulators rescaled per sub-tile. Emits m,l,O per big-chunk.
// ---------------------------------------------------------------------------
__launch_bounds__(256, 1)
__global__ void k_attn_flash(const float* __restrict__ Q, const float* __restrict__ K,
                             const float* __restrict__ V, const int* __restrict__ topIdx,
                             float* __restrict__ mc, float* __restrict__ lc,
                             float* __restrict__ Oc)
{
    __shared__ float sK[KC][KPAD];
    __shared__ float sV[KC][KPAD];
    __shared__ float sP[UU][PPAD];
    __shared__ int   sPos[UU];
    __shared__ float sM[UU], sL[UU], sScale[UU];

    int t   = threadIdx.x;
    int bh  = blockIdx.x / NBIG, big = blockIdx.x % NBIG;
    int b   = bh / HH, h = bh % HH;

    if (t < UU) {
        sPos[t]   = topIdx[bh * UU + t];
        sM[t]     = -INFINITY;
        sL[t]     = 0.f;
    }

    // persistent O accumulators: thread = (d4p = t&15, ug = t>>4)
    int d4p = t & 15, ug = t >> 4;
    int u0 = ug, u1 = 16 + ug, u2 = 32 + ug;
    int u2c = (u2 < UU) ? u2 : (UU - 1);       // clamped; result discarded
    float4 a0 = {0,0,0,0}, a1 = {0,0,0,0}, a2 = {0,0,0,0};

    int j  = t & 63;                            // QK lane -> K row
    int w  = t >> 6, lane = t & 63;             // softmax wave mapping
    int ub = __builtin_amdgcn_readfirstlane(w) * 10;

    for (int sub = 0; sub < NSUB; ++sub) {
        int k0 = (big * NSUB + sub) * KC;
        __syncthreads();   // previous Phase D (and sub=0 sPos write) done

        // ---- stage K/V tile (64 rows x 64 floats), coalesced float4 ----
        const float* Kbase = K + (((size_t)b * LL + k0) * HH + h) * DD;
        const float* Vbase = V + (((size_t)b * LL + k0) * HH + h) * DD;
        #pragma unroll
        for (int it = 0; it < 4; ++it) {
            int flat = it * 256 + t;            // 0..1023
            int r = flat >> 4, d4 = flat & 15;
            float4 kk = *(const float4*)(Kbase + (size_t)r * (HH * DD) + d4 * 4);
            float4 vv = *(const float4*)(Vbase + (size_t)r * (HH * DD) + d4 * 4);
            *(float4*)&sK[r][d4 * 4] = kk;
            *(float4*)&sV[r][d4 * 4] = vv;
        }
        __syncthreads();

        // ---- QK: lane owns K row j; Q rows via scalar (wave-uniform) loads ----
        int jg = k0 + j;
        float kreg[DD];
        #pragma unroll
        for (int d4 = 0; d4 < 16; ++d4) {
            float4 kk = *(const float4*)&sK[j][d4 * 4];
            kreg[d4 * 4 + 0] = kk.x; kreg[d4 * 4 + 1] = kk.y;
            kreg[d4 * 4 + 2] = kk.z; kreg[d4 * 4 + 3] = kk.w;
        }
        #pragma unroll
        for (int iu = 0; iu < 10; iu += 5) {
            int p0 = __builtin_amdgcn_readfirstlane(sPos[ub + iu + 0]);
            int p1 = __builtin_amdgcn_readfirstlane(sPos[ub + iu + 1]);
            int p2 = __builtin_amdgcn_readfirstlane(sPos[ub + iu + 2]);
            int p3 = __builtin_amdgcn_readfirstlane(sPos[ub + iu + 3]);
            int p4 = __builtin_amdgcn_readfirstlane(sPos[ub + iu + 4]);
            const float* q0 = Q + (((size_t)b * LL + p0) * HH + h) * DD;
            const float* q1 = Q + (((size_t)b * LL + p1) * HH + h) * DD;
            const float* q2 = Q + (((size_t)b * LL + p2) * HH + h) * DD;
            const float* q3 = Q + (((size_t)b * LL + p3) * HH + h) * DD;
            const float* q4 = Q + (((size_t)b * LL + p4) * HH + h) * DD;
            float c0 = 0.f, c1 = 0.f, c2 = 0.f, c3 = 0.f, c4 = 0.f;
            #pragma unroll
            for (int d = 0; d < DD; ++d) {
                float kd = kreg[d];
                c0 = fmaf(q0[d], kd, c0);
                c1 = fmaf(q1[d], kd, c1);
                c2 = fmaf(q2[d], kd, c2);
                c3 = fmaf(q3[d], kd, c3);
                c4 = fmaf(q4[d], kd, c4);
            }
            sP[ub + iu + 0][j] = (jg > p0) ? -INFINITY : c0 * 0.125f;
            sP[ub + iu + 1][j] = (jg > p1) ? -INFINITY : c1 * 0.125f;
            sP[ub + iu + 2][j] = (jg > p2) ? -INFINITY : c2 * 0.125f;
            sP[ub + iu + 3][j] = (jg > p3) ? -INFINITY : c3 * 0.125f;
            sP[ub + iu + 4][j] = (jg > p4) ? -INFINITY : c4 * 0.125f;
        }
        __syncthreads();

        // ---- online softmax stats; wave w handles u = w*10 .. +9 ----
        for (int i = 0; i < 10; ++i) {
            int u = w * 10 + i;
            float s0 = sP[u][lane];
            float mchunk = s0;
            #pragma unroll
            for (int off = 1; off < 64; off <<= 1)
                mchunk = fmaxf(mchunk, __shfl_xor(mchunk, off));
            float mold = sM[u];
            float mnew = fmaxf(mold, mchunk);
            float e = (mnew == -INFINITY) ? 0.f : __expf(s0 - mnew);
            float lch = e;
            #pragma unroll
            for (int off = 1; off < 64; off <<= 1) lch += __shfl_xor(lch, off);
            float scale = (mold == -INFINITY) ? 0.f : __expf(mold - mnew);
            sP[u][lane] = e;
            if (lane == 0) {
                sM[u] = mnew;
                sL[u] = sL[u] * scale + lch;
                sScale[u] = scale;
            }
        }
        __syncthreads();

        // ---- PV accumulate with rescale ----
        float sc0 = sScale[u0], sc1 = sScale[u1], sc2 = sScale[u2c];
        a0.x *= sc0; a0.y *= sc0; a0.z *= sc0; a0.w *= sc0;
        a1.x *= sc1; a1.y *= sc1; a1.z *= sc1; a1.w *= sc1;
        a2.x *= sc2; a2.y *= sc2; a2.z *= sc2; a2.w *= sc2;
        #pragma unroll 4
        for (int j4 = 0; j4 < KC / 4; ++j4) {
            float4 pj0 = *(const float4*)&sP[u0][j4 * 4];
            float4 pj1 = *(const float4*)&sP[u1][j4 * 4];
            float4 pj2 = *(const float4*)&sP[u2c][j4 * 4];
            float4 va = *(const float4*)&sV[j4 * 4 + 0][d4p * 4];
            float4 vb = *(const float4*)&sV[j4 * 4 + 1][d4p * 4];
            float4 vc = *(const float4*)&sV[j4 * 4 + 2][d4p * 4];
            float4 vd = *(const float4*)&sV[j4 * 4 + 3][d4p * 4];
            a0.x = fmaf(pj0.x, va.x, fmaf(pj0.y, vb.x, fmaf(pj0.z, vc.x, fmaf(pj0.w, vd.x, a0.x))));
            a0.y = fmaf(pj0.x, va.y, fmaf(pj0.y, vb.y, fmaf(pj0.z, vc.y, fmaf(pj0.w, vd.y, a0.y))));
            a0.z = fmaf(pj0.x, va.z, fmaf(pj0.y, vb.z, fmaf(pj0.z, vc.z, fmaf(pj0.w, vd.z, a0.z))));
            a0.w = fmaf(pj0.x, va.w, fmaf(pj0.y, vb.w, fmaf(pj0.z, vc.w, fmaf(pj0.w, vd.w, a0.w))));
            a1.x = fmaf(pj1.x, va.x, fmaf(pj1.y, vb.x, fmaf(pj1.z, vc.x, fmaf(pj1.w, vd.x, a1.x))));
            a1.y = fmaf(pj1.x, va.y, fmaf(pj1.y, vb.y, fmaf(pj1.z, vc.y, fmaf(pj1.w, vd.y, a1.y))));
            a1.z = fmaf(pj1.x, va.z, fmaf(pj1.y, vb.z, fmaf(pj1.z, vc.z, fmaf(pj1.w, vd.z, a1.z))));
            a1.w = fmaf(pj1.x, va.w, fmaf(pj1.y, vb.w, fmaf(pj1.z, vc.w, fmaf(pj1.w, vd.w, a1.w))));
            a2.x = fmaf(pj2.x, va.x, fmaf(pj2.y, vb.x, fmaf(pj2.z, vc.x, fmaf(pj2.w, vd.x, a2.x))));
            a2.y = fmaf(pj2.x, va.y, fmaf(pj2.y, vb.y, fmaf(pj2.z, vc.y, fmaf(pj2.w, vd.y, a2.y))));
            a2.z = fmaf(pj2.x, va.z, fmaf(pj2.y, vb.z, fmaf(pj2.z, vc.z, fmaf(pj2.w, vd.z, a2.z))));
            a2.w = fmaf(pj2.x, va.w, fmaf(pj2.y, vb.w, fmaf(pj2.z, vc.w, fmaf(pj2.w, vd.w, a2.w))));
        }
    }
    __syncthreads();

    int cidx = (bh * NBIG + big) * UU;
    float* ob = Oc + (size_t)cidx * DD;
    *(float4*)&ob[u0 * DD + d4p * 4] = a0;
    *(float4*)&ob[u1 * DD + d4p * 4] = a1;
    if (u2 < UU) *(float4*)&ob[u2 * DD + d4p * 4] = a2;
    if (t < UU) { mc[cidx + t] = sM[t]; lc[cidx + t] = sL[t]; }
}

// ---------------------------------------------------------------------------
// K4: combine the 8 big-chunk partials and write into out rows.
// Must run after k_cumsum. Grid = 32 bh, 256 threads.
// ---------------------------------------------------------------------------
__global__ void k_combine(const float* __restrict__ mc, const float* __restrict__ lc,
                          const float* __restrict__ Oc, const int* __restrict__ topIdx,
                          float* __restrict__ out)
{
    int bh = blockIdx.x;
    int b  = bh / HH, h = bh % HH;
    int t  = threadIdx.x;
    int d  = t & 63, ug = t >> 6;
    for (int i = 0; i < 10; ++i) {
        int u = ug * 10 + i;
        int pos = topIdx[bh * UU + u];
        float Mx = -INFINITY;
        for (int c = 0; c < NBIG; ++c)
            Mx = fmaxf(Mx, mc[(bh * NBIG + c) * UU + u]);
        float Os = 0.f, Ls = 0.f;
        for (int c = 0; c < NBIG; ++c) {
            int ci = (bh * NBIG + c) * UU + u;
            float m = mc[ci];
            float wgt = (m == -INFINITY) ? 0.f : __expf(m - Mx);
            Ls += wgt * lc[ci];
            Os += wgt * Oc[(size_t)ci * DD + d];
        }
        out[(((size_t)b * LL + pos) * HH + h) * DD + d] = Os / Ls;
    }
}

// ---------------------------------------------------------------------------
// K5a: per-chunk sums of V along L (for cumsum). Block = 64 threads.
// ---------------------------------------------------------------------------
__global__ void k_chunksum(const float* __restrict__ V, float* __restrict__ chunkSum)
{
    int lane = threadIdx.x;
    int c  = blockIdx.x % CC;
    int bh = blockIdx.x / CC;
    int b  = bh / HH; int h = bh - b * HH;
    float acc = 0.f;
    int l0 = c * LC;
    for (int l = l0; l < l0 + LC; ++l)
        acc += V[(((size_t)b * LL + l) * HH + h) * DD + lane];
    chunkSum[((size_t)bh * CC + c) * DD + lane] = acc;
}

// ---------------------------------------------------------------------------
// K5b: cumsum with chunk-offset, write fp32 output (B,L,H,D layout).
// ---------------------------------------------------------------------------
__global__ void k_cumsum(const float* __restrict__ V, const float* __restrict__ chunkSum,
                         float* __restrict__ out)
{
    int lane = threadIdx.x;
    int c  = blockIdx.x % CC;
    int bh = blockIdx.x / CC;
    int b  = bh / HH; int h = bh - b * HH;

    float off = 0.f;
    for (int c2 = 0; c2 < c; ++c2)
        off += chunkSum[((size_t)bh * CC + c2) * DD + lane];

    float acc = off;
    int l0 = c * LC;
    for (int l = l0; l < l0 + LC; ++l) {
        size_t p = (((size_t)b * LL + l) * HH + h) * DD + lane;
        acc += V[p];
        out[p] = acc;
    }
}

// ---------------------------------------------------------------------------
extern "C" void kernel_launch(void* const* d_in, const int* in_sizes, int n_in,
                              void* d_out, int out_size, void* d_ws, size_t ws_size,
                              hipStream_t stream)
{
    const float* Q   = (const float*)d_in[0];
    const float* K   = (const float*)d_in[1];
    const float* V   = (const float*)d_in[2];
    const int*   idx = (const int*)d_in[3];
    float* out = (float*)d_out;

    // ws layout (floats) — total ~874K floats ≈ 3.5 MB
    float* M        = (float*)d_ws;                               // 65536
    int*   topIdx   = (int*)(M + (size_t)BB * HH * LL);           // 1280
    float* mc       = (float*)(topIdx + BB * HH * UU);            // 32*NBIG*UU
    float* lc       = mc + (size_t)BB * HH * NBIG * UU;           // 32*NBIG*UU
    float* Oc       = lc + (size_t)BB * HH * NBIG * UU;           // 32*NBIG*UU*DD
    float* chunkSum = Oc + (size_t)BB * HH * NBIG * UU * DD;      // 32*CC*DD

    k_measure   <<<BB * HH * LL / 4, 256, 0, stream>>>(Q, K, idx, M);
    k_topk      <<<BB * HH,           64, 0, stream>>>(M, topIdx);
    k_attn_flash<<<BB * HH * NBIG,   256, 0, stream>>>(Q, K, V, topIdx, mc, lc, Oc);
    k_chunksum  <<<BB * HH * CC,      64, 0, stream>>>(V, chunkSum);
    k_cumsum    <<<BB * HH * CC,      64, 0, stream>>>(V, chunkSum, out);
    k_combine   <<<BB * HH,          256, 0, stream>>>(mc, lc, Oc, topIdx, out);
}